// Round 3
// baseline (4139.521 us; speedup 1.0000x reference)
//
#include <hip/hip_runtime.h>
#include <math.h>
#include <stdint.h>

#define NTRY  50
#define BROWS 131072
// output section offsets (floats): out[B*7] | mu[B*32] | kappa[B]
#define OFF_OUT_MU    917504
#define OFF_OUT_KAPPA 5111808

__device__ __forceinline__ uint32_t rotl32(uint32_t x, int r){ return (x << r) | (x >> (32 - r)); }

// Exact JAX threefry2x32 (20 rounds, 5 key injections)
__device__ __forceinline__ void threefry2x32(uint32_t k0, uint32_t k1,
                                             uint32_t c0, uint32_t c1,
                                             uint32_t& o0, uint32_t& o1){
  const uint32_t k2 = k0 ^ k1 ^ 0x1BD11BDAu;
  uint32_t x0 = c0 + k0;
  uint32_t x1 = c1 + k1;
#define TF_R(r) { x0 += x1; x1 = rotl32(x1, (r)); x1 ^= x0; }
  TF_R(13) TF_R(15) TF_R(26) TF_R(6)
  x0 += k1; x1 += k2 + 1u;
  TF_R(17) TF_R(29) TF_R(16) TF_R(24)
  x0 += k2; x1 += k0 + 2u;
  TF_R(13) TF_R(15) TF_R(26) TF_R(6)
  x0 += k0; x1 += k1 + 3u;
  TF_R(17) TF_R(29) TF_R(16) TF_R(24)
  x0 += k1; x1 += k2 + 4u;
  TF_R(13) TF_R(15) TF_R(26) TF_R(6)
  x0 += k2; x1 += k0 + 5u;
#undef TF_R
  o0 = x0; o1 = x1;
}

// Partitionable random_bits (bit_width=32): bits = out0 ^ out1, counter=(0, idx)
__device__ __forceinline__ uint32_t tf_bits32(uint32_t k0, uint32_t k1, uint32_t idx){
  uint32_t a, b;
  threefry2x32(k0, k1, 0u, idx, a, b);
  return a ^ b;
}

// JAX uniform bit->float: (bits>>9)|0x3f800000 as float, minus 1 -> [0,1)
__device__ __forceinline__ float bits_to_unit(uint32_t bits){
  return __uint_as_float((bits >> 9) | 0x3f800000u) - 1.0f;
}

// f32 log computed via f64 (≈ correctly rounded f32 log) — must stay: acceptance ties
__device__ __forceinline__ float alogf(float x){
  return (float)log((double)x);
}

// XLA f32 ErfInv polynomial (Giles)
__device__ __forceinline__ float erfinv_f(float x){
  float w = -log1pf(-x * x);
  float p;
  if (w < 5.0f){
    w -= 2.5f;
    p = 2.81022636e-08f;
    p = fmaf(p, w, 3.43273939e-07f);
    p = fmaf(p, w, -3.5233877e-06f);
    p = fmaf(p, w, -4.39150654e-06f);
    p = fmaf(p, w, 0.00021858087f);
    p = fmaf(p, w, -0.00125372503f);
    p = fmaf(p, w, -0.00417768164f);
    p = fmaf(p, w, 0.246640727f);
    p = fmaf(p, w, 1.50140941f);
  } else {
    w = sqrtf(w) - 3.0f;
    p = -0.000200214257f;
    p = fmaf(p, w, 0.000100950558f);
    p = fmaf(p, w, 0.00134934322f);
    p = fmaf(p, w, -0.00367342844f);
    p = fmaf(p, w, 0.00573950773f);
    p = fmaf(p, w, -0.0076224613f);
    p = fmaf(p, w, 0.00943887047f);
    p = fmaf(p, w, 1.00167406f);
    p = fmaf(p, w, 2.83297682f);
  }
  return p * x;
}

// ws: keys u32[0..200) = 50 * {k1.x,k1.y,k2.x,k2.y}; u32[200..202) = kv
//     float W2T[512][32] at byte offset 1024
__global__ void prep_kernel(const float* __restrict__ W2, const int* __restrict__ seedp,
                            uint32_t* __restrict__ keys, float* __restrict__ W2T)
{
  const int t = threadIdx.x;
  if (blockIdx.x == 0){
    const uint32_t seed = (uint32_t)seedp[0];
    if (t < NTRY){
      uint32_t f0, f1, a0, a1, b0, b1;
      threefry2x32(0u, seed, 0u, (uint32_t)t, f0, f1);
      threefry2x32(f0, f1, 0u, 0u, a0, a1);   // k1 = split[0]
      threefry2x32(f0, f1, 0u, 1u, b0, b1);   // k2 = split[1]
      keys[t*4+0] = a0; keys[t*4+1] = a1;
      keys[t*4+2] = b0; keys[t*4+3] = b1;
    } else if (t == NTRY){
      uint32_t f0, f1;
      threefry2x32(0u, seed, 0u, 10000u, f0, f1);
      keys[200] = f0; keys[201] = f1;
    }
  }
  // transpose W2 [32,512] -> W2T [512,32]; 32 blocks x 512 elements
  const int base = blockIdx.x * 512;
  for (int i = base + t; i < base + 512; i += 256){
    int o2 = i >> 9, o1 = i & 511;
    W2T[o1*32 + o2] = W2[i];
  }
}

// 4 waves cooperate on 64 rows: lane = row-in-block, sub = wave id (phase slice).
__global__ __launch_bounds__(256, 6) void fused_kernel(
    const float* __restrict__ h,
    const float* __restrict__ Wmu, const float* __restrict__ bmu,
    const float* __restrict__ Wk,  const float* __restrict__ bk,
    const float* __restrict__ W1,  const float* __restrict__ b1,
    const float* __restrict__ b2,
    const float* __restrict__ W3,  const float* __restrict__ b3,
    const float* __restrict__ W2T,
    const uint32_t* __restrict__ keys,
    float* __restrict__ out)
{
  __shared__ float mush[64*33];   // mu+bias (raw, pre-norm); stride 33 (2-way banks = free)
  __shared__ float vsh[64*33];    // normals; REUSED as x2 accumulator in phase C
  __shared__ float ksh[64];
  __shared__ int   idxsh[256];
  __shared__ float wsh[256];

  const int lane = threadIdx.x & 63;
  const int sub  = threadIdx.x >> 6;       // wave-uniform
  const int row  = blockIdx.x * 64 + lane;

  // ---------------- phase A: wave sub computes dots [8*sub, 8*sub+8), full K=512 ----
  float macc[8]; float kacc = 0.f;
  #pragma unroll
  for (int i = 0; i < 8; ++i) macc[i] = 0.f;
  const float4* h4 = reinterpret_cast<const float4*>(h + (size_t)row * 512);
  const int obase = sub * 8;
  #pragma unroll 1
  for (int ch = 0; ch < 16; ++ch){
    float hv[32];
    #pragma unroll
    for (int q = 0; q < 8; ++q){
      float4 f = h4[ch*8 + q];
      hv[q*4+0] = f.x; hv[q*4+1] = f.y; hv[q*4+2] = f.z; hv[q*4+3] = f.w;
    }
    #pragma unroll
    for (int i = 0; i < 8; ++i){
      const float* wr = Wmu + (obase + i)*512 + ch*32;   // wave-uniform -> s_load
      float a = macc[i];
      #pragma unroll
      for (int c = 0; c < 32; ++c) a += hv[c] * wr[c];
      macc[i] = a;
    }
    if (sub == 3){                                        // wave-uniform branch
      const float* wr = Wk + ch*32;
      float a = kacc;
      #pragma unroll
      for (int c = 0; c < 32; ++c) a += hv[c] * wr[c];
      kacc = a;
    }
  }
  #pragma unroll
  for (int i = 0; i < 8; ++i) mush[lane*33 + obase + i] = macc[i] + bmu[obase + i];
  if (sub == 3){
    const float xk = kacc + bk[0];
    const float kap = (float)log1p(exp((double)xk)) + 1.0f;  // softplus+1
    ksh[lane] = kap;
    out[OFF_OUT_KAPPA + row] = kap;
  }
  __syncthreads();

  // All lanes: mu norm (sequential over 32 -> bit-identical to R2)
  float nsq = 0.f;
  #pragma unroll
  for (int o = 0; o < 32; ++o){ float m = mush[lane*33 + o]; nsq += m*m; }
  const float invn  = 1.0f / fmaxf(sqrtf(nsq), 1e-12f);
  const float kappa = ksh[lane];

  if (sub == 0){  // write mu output
    float4* mo = reinterpret_cast<float4*>(out + OFF_OUT_MU + (size_t)row * 32);
    #pragma unroll
    for (int q = 0; q < 8; ++q){
      float4 f;
      f.x = mush[lane*33 + q*4+0] * invn;
      f.y = mush[lane*33 + q*4+1] * invn;
      f.z = mush[lane*33 + q*4+2] * invn;
      f.w = mush[lane*33 + q*4+3] * invn;
      mo[q] = f;
    }
  }

  // ---------------- phase B: rejection tries interleaved mod 4 across waves ---------
  int   idx = NTRY;  float myw = 0.f;
  {
    #pragma clang fp contract(off)
    bool done = false;
    #pragma unroll 1
    for (int k = 0; k < 13; ++k){
      const int t4 = 4*k + sub;                       // wave-uniform
      const int tc = (t4 < NTRY) ? t4 : (NTRY - 1);
      const uint32_t K0 = keys[tc*4+0], K1 = keys[tc*4+1];  // s_load
      const uint32_t K2 = keys[tc*4+2], K3 = keys[tc*4+3];
      if (t4 < NTRY && !done){
        const float u1 = bits_to_unit(tf_bits32(K0, K1, (uint32_t)row));
        const float u2 = bits_to_unit(tf_bits32(K2, K3, (uint32_t)row));
        const float wc   = 2.0f * u1 - 1.0f;
        const float omw2 = fmaxf(1.0f - wc*wc, 1e-38f);
        const float lp   = kappa * wc + 14.5f * alogf(omw2);
        const float lr   = alogf(u2 + 1e-38f);
        if (lr + kappa <= lp){ done = true; idx = t4; myw = wc; }
      }
      const bool fin = done || (4*(k+1) + sub >= NTRY);
      if (__ballot(!fin) == 0ull) break;              // all 64 rows' slice done
    }
  }
  idxsh[sub*64 + lane] = idx;
  wsh [sub*64 + lane] = myw;

  // normals: wave sub computes j in {sub, sub+4, ...}
  {
    const uint32_t kv0 = keys[200], kv1 = keys[201];
    const uint32_t e0 = (uint32_t)row * 31u;
    #pragma unroll
    for (int i = 0; i < 8; ++i){
      const int j = 4*i + sub;                        // wave-uniform
      if (j < 31){
        const float uf01 = bits_to_unit(tf_bits32(kv0, kv1, e0 + (uint32_t)j));
        const float uu = fmaxf(uf01 * 2.0f + (-0.99999994f), -0.99999994f);
        vsh[lane*33 + j] = 1.4142135623730951f * erfinv_f(uu);
      }
    }
  }
  __syncthreads();

  // combine first-accept across the 4 try-slices (min try index) — bit-exact
  int bidx = NTRY; float w = 0.f;
  #pragma unroll
  for (int s = 0; s < 4; ++s){
    int   ii = idxsh[s*64 + lane];
    float ww = wsh [s*64 + lane];
    if (ii < bidx){ bidx = ii; w = ww; }
  }
  w = fminf(fmaxf(w, -1.0f), 1.0f);

  float vns = 0.f;
  #pragma unroll
  for (int j = 0; j < 31; ++j){ float g = vsh[lane*33 + j]; vns += g*g; }
  const float invvn = 1.0f / fmaxf(sqrtf(vns), 1e-12f);
  const float st    = sqrtf(fmaxf(1.0f - w*w, 1e-38f));

  // Householder (mu_n recomputed from LDS; same ops as R2 -> same values)
  float uns = 0.f;
  #pragma unroll
  for (int o = 0; o < 32; ++o){
    float mu_n = mush[lane*33 + o] * invn;
    float e = ((o == 31) ? 1.0f : 0.0f) - mu_n;
    uns += e*e;
  }
  const float invun = 1.0f / fmaxf(sqrtf(uns), 1e-12f);
  float dot = 0.f;
  #pragma unroll
  for (int o = 0; o < 32; ++o){
    float mu_n = mush[lane*33 + o] * invn;
    float ue = (((o == 31) ? 1.0f : 0.0f) - mu_n) * invun;
    float zt = (o < 31) ? st * (vsh[lane*33 + o] * invvn) : w;
    dot += zt * ue;
  }
  float z[32];
  #pragma unroll
  for (int o = 0; o < 32; ++o){
    float mu_n = mush[lane*33 + o] * invn;
    float ue = (((o == 31) ? 1.0f : 0.0f) - mu_n) * invun;
    float zt = (o < 31) ? st * (vsh[lane*33 + o] * invvn) : w;
    z[o] = zt - 2.0f * dot * ue;
  }

  // ---------------- phase C: MLP, o1 split 128/wave, LDS-atomic reduce --------------
  __syncthreads();                       // all done reading vsh
  for (int i = threadIdx.x; i < 64*33; i += 256) vsh[i] = 0.f;
  __syncthreads();

  float x2p[32];
  #pragma unroll
  for (int o2 = 0; o2 < 32; ++o2) x2p[o2] = 0.f;
  const int o1base = sub * 128;
  #pragma unroll 2
  for (int q = 0; q < 128; ++q){
    const int o1 = o1base + q;
    const float* w1r = W1 + o1*32;       // wave-uniform -> s_load
    float t = b1[o1];
    #pragma unroll
    for (int j = 0; j < 32; ++j) t += z[j] * w1r[j];
    t = fmaxf(t, 0.f);
    const float* w2r = W2T + o1*32;      // wave-uniform -> s_load
    #pragma unroll
    for (int o2 = 0; o2 < 32; ++o2) x2p[o2] += t * w2r[o2];
  }
  #pragma unroll
  for (int o2 = 0; o2 < 32; ++o2) atomicAdd(&vsh[lane*33 + o2], x2p[o2]);
  __syncthreads();

  // epilogue: wave sub computes outputs k in {sub, sub+4}
  for (int kk = sub; kk < 7; kk += 4){
    const float* w3r = W3 + kk*32;       // wave-uniform -> s_load
    float s = b3[kk];
    #pragma unroll
    for (int o2 = 0; o2 < 32; ++o2){
      float x2 = fmaxf(vsh[lane*33 + o2] + b2[o2], 0.f);
      s += x2 * w3r[o2];
    }
    out[(size_t)row*7 + kk] = s;
  }
}

extern "C" void kernel_launch(void* const* d_in, const int* in_sizes, int n_in,
                              void* d_out, int out_size, void* d_ws, size_t ws_size,
                              hipStream_t stream)
{
  const float* h   = (const float*)d_in[0];
  const float* Wmu = (const float*)d_in[1];
  const float* bmu = (const float*)d_in[2];
  const float* Wk  = (const float*)d_in[3];
  const float* bk  = (const float*)d_in[4];
  const float* W1  = (const float*)d_in[5];
  const float* b1  = (const float*)d_in[6];
  const float* W2  = (const float*)d_in[7];
  const float* b2  = (const float*)d_in[8];
  const float* W3  = (const float*)d_in[9];
  const float* b3  = (const float*)d_in[10];
  const int* seed  = (const int*)d_in[11];

  uint32_t* keys = (uint32_t*)d_ws;
  float* W2T = (float*)((char*)d_ws + 1024);
  float* out = (float*)d_out;

  hipLaunchKernelGGL(prep_kernel, dim3(32), dim3(256), 0, stream, W2, seed, keys, W2T);
  hipLaunchKernelGGL(fused_kernel, dim3(BROWS/64), dim3(256), 0, stream,
                     h, Wmu, bmu, Wk, bk, W1, b1, b2, W3, b3, W2T, keys, out);
}

// Round 4
// 4120.324 us; speedup vs baseline: 1.0047x; 1.0047x over previous
//
#include <hip/hip_runtime.h>
#include <math.h>
#include <stdint.h>

#define NTRY  50
#define BROWS 131072
// output section offsets (floats): out[B*7] | mu[B*32] | kappa[B]
#define OFF_OUT_MU    917504
#define OFF_OUT_KAPPA 5111808

__device__ __forceinline__ uint32_t rotl32(uint32_t x, int r){ return (x << r) | (x >> (32 - r)); }

// Exact JAX threefry2x32 (20 rounds, 5 key injections)
__device__ __forceinline__ void threefry2x32(uint32_t k0, uint32_t k1,
                                             uint32_t c0, uint32_t c1,
                                             uint32_t& o0, uint32_t& o1){
  const uint32_t k2 = k0 ^ k1 ^ 0x1BD11BDAu;
  uint32_t x0 = c0 + k0;
  uint32_t x1 = c1 + k1;
#define TF_R(r) { x0 += x1; x1 = rotl32(x1, (r)); x1 ^= x0; }
  TF_R(13) TF_R(15) TF_R(26) TF_R(6)
  x0 += k1; x1 += k2 + 1u;
  TF_R(17) TF_R(29) TF_R(16) TF_R(24)
  x0 += k2; x1 += k0 + 2u;
  TF_R(13) TF_R(15) TF_R(26) TF_R(6)
  x0 += k0; x1 += k1 + 3u;
  TF_R(17) TF_R(29) TF_R(16) TF_R(24)
  x0 += k1; x1 += k2 + 4u;
  TF_R(13) TF_R(15) TF_R(26) TF_R(6)
  x0 += k2; x1 += k0 + 5u;
#undef TF_R
  o0 = x0; o1 = x1;
}

// Partitionable random_bits (bit_width=32): bits = out0 ^ out1, counter=(0, idx)
__device__ __forceinline__ uint32_t tf_bits32(uint32_t k0, uint32_t k1, uint32_t idx){
  uint32_t a, b;
  threefry2x32(k0, k1, 0u, idx, a, b);
  return a ^ b;
}

// JAX uniform bit->float: (bits>>9)|0x3f800000 as float, minus 1 -> [0,1)
__device__ __forceinline__ float bits_to_unit(uint32_t bits){
  return __uint_as_float((bits >> 9) | 0x3f800000u) - 1.0f;
}

// f32 log via f64 (≈ correctly rounded) — feeds acceptance ties, keep exact
__device__ __forceinline__ float alogf(float x){
  return (float)log((double)x);
}

// XLA f32 ErfInv polynomial (Giles)
__device__ __forceinline__ float erfinv_f(float x){
  float w = -log1pf(-x * x);
  float p;
  if (w < 5.0f){
    w -= 2.5f;
    p = 2.81022636e-08f;
    p = fmaf(p, w, 3.43273939e-07f);
    p = fmaf(p, w, -3.5233877e-06f);
    p = fmaf(p, w, -4.39150654e-06f);
    p = fmaf(p, w, 0.00021858087f);
    p = fmaf(p, w, -0.00125372503f);
    p = fmaf(p, w, -0.00417768164f);
    p = fmaf(p, w, 0.246640727f);
    p = fmaf(p, w, 1.50140941f);
  } else {
    w = sqrtf(w) - 3.0f;
    p = -0.000200214257f;
    p = fmaf(p, w, 0.000100950558f);
    p = fmaf(p, w, 0.00134934322f);
    p = fmaf(p, w, -0.00367342844f);
    p = fmaf(p, w, 0.00573950773f);
    p = fmaf(p, w, -0.0076224613f);
    p = fmaf(p, w, 0.00943887047f);
    p = fmaf(p, w, 1.00167406f);
    p = fmaf(p, w, 2.83297682f);
  }
  return p * x;
}

// ws: keys u32[0..200) = 50 * {k1.x,k1.y,k2.x,k2.y}; u32[200..202) = kv
//     float W2T[512][32] at byte offset 1024
__global__ void prep_kernel(const float* __restrict__ W2, const int* __restrict__ seedp,
                            uint32_t* __restrict__ keys, float* __restrict__ W2T)
{
  const int t = threadIdx.x;
  if (blockIdx.x == 0){
    const uint32_t seed = (uint32_t)seedp[0];
    if (t < NTRY){
      uint32_t f0, f1, a0, a1, b0, b1;
      threefry2x32(0u, seed, 0u, (uint32_t)t, f0, f1);
      threefry2x32(f0, f1, 0u, 0u, a0, a1);   // k1 = split[0]
      threefry2x32(f0, f1, 0u, 1u, b0, b1);   // k2 = split[1]
      keys[t*4+0] = a0; keys[t*4+1] = a1;
      keys[t*4+2] = b0; keys[t*4+3] = b1;
    } else if (t == NTRY){
      uint32_t f0, f1;
      threefry2x32(0u, seed, 0u, 10000u, f0, f1);
      keys[200] = f0; keys[201] = f1;
    }
  }
  const int base = blockIdx.x * 512;
  for (int i = base + t; i < base + 512; i += 256){
    int o2 = i >> 9, o1 = i & 511;
    W2T[o1*32 + o2] = W2[i];
  }
}

// 2 threads cooperate per row. r = tid&127 (row in block), p = tid>>7 (pair half).
// Waves 0-1: p=0 rows 0..127; waves 2-3: p=1 rows 0..127. p is wave-uniform.
// VGPR live set: phase A hv[32]+acc[17] (~60), phase C z[32]+x2p[32] (~75).
// __launch_bounds__(256,4): 128 VGPR cap -> 4 waves/SIMD, NO spills (R3 lesson).
__global__ __launch_bounds__(256, 4) void fused_kernel(
    const float* __restrict__ h,
    const float* __restrict__ Wmu, const float* __restrict__ bmu,
    const float* __restrict__ Wk,  const float* __restrict__ bk,
    const float* __restrict__ W1,  const float* __restrict__ b1,
    const float* __restrict__ b2,
    const float* __restrict__ W3,  const float* __restrict__ b3,
    const float* __restrict__ W2T,
    const uint32_t* __restrict__ keys,
    float* __restrict__ out)
{
  __shared__ float mush[128*33];   // raw mu+bias; later: x2 partial (p=0). stride 33
  __shared__ float vsh[128*33];    // normals;     later: x2 partial (p=1)
  __shared__ float ksh[128];
  __shared__ int   idxsh[256];
  __shared__ float wsh[256];

  const int r   = threadIdx.x & 127;
  const int p   = threadIdx.x >> 7;        // wave-uniform
  const int row = blockIdx.x * 128 + r;

  // ---------- phase A: p=0 -> mu dots 0..15; p=1 -> mu dots 16..31 + kappa ---------
  // Each dot is full K=512, chunk-sequential -> bit-identical to R2's values.
  float acc[17];
  #pragma unroll
  for (int i = 0; i < 17; ++i) acc[i] = 0.f;
  const float4* h4 = reinterpret_cast<const float4*>(h + (size_t)row * 512);
  const int obase = p * 16;
  #pragma unroll 1
  for (int ch = 0; ch < 16; ++ch){
    float hv[32];
    #pragma unroll
    for (int q = 0; q < 8; ++q){
      float4 f = h4[ch*8 + q];
      hv[q*4+0] = f.x; hv[q*4+1] = f.y; hv[q*4+2] = f.z; hv[q*4+3] = f.w;
    }
    #pragma unroll
    for (int i = 0; i < 16; ++i){
      const float* wr = Wmu + (obase + i)*512 + ch*32;   // wave-uniform -> s_load
      float a = acc[i];
      #pragma unroll
      for (int c = 0; c < 32; ++c) a += hv[c] * wr[c];
      acc[i] = a;
    }
    if (p == 1){                                          // wave-uniform branch
      const float* wr = Wk + ch*32;
      float a = acc[16];
      #pragma unroll
      for (int c = 0; c < 32; ++c) a += hv[c] * wr[c];
      acc[16] = a;
    }
  }
  #pragma unroll
  for (int i = 0; i < 16; ++i) mush[r*33 + obase + i] = acc[i] + bmu[obase + i];
  if (p == 1){
    const float xk = acc[16] + bk[0];
    const float kap = (float)log1p(exp((double)xk)) + 1.0f;  // softplus+1, exact
    ksh[r] = kap;
    out[OFF_OUT_KAPPA + row] = kap;
  }
  __syncthreads();

  // mu norm: sequential over 32 (bit-identical), both threads compute
  float nsq = 0.f;
  #pragma unroll
  for (int o = 0; o < 32; ++o){ float m = mush[r*33 + o]; nsq += m*m; }
  const float invn  = 1.0f / fmaxf(sqrtf(nsq), 1e-12f);
  const float kappa = ksh[r];

  if (p == 0){  // write mu output
    float4* mo = reinterpret_cast<float4*>(out + OFF_OUT_MU + (size_t)row * 32);
    #pragma unroll
    for (int q = 0; q < 8; ++q){
      float4 f;
      f.x = mush[r*33 + q*4+0] * invn;
      f.y = mush[r*33 + q*4+1] * invn;
      f.z = mush[r*33 + q*4+2] * invn;
      f.w = mush[r*33 + q*4+3] * invn;
      mo[q] = f;
    }
  }

  // ---------- phase B: tries interleaved even/odd; ballot early-exit ---------------
  int idx = NTRY; float myw = 0.f;
  {
    #pragma clang fp contract(off)
    bool done = false;
    #pragma unroll 1
    for (int k = 0; k < 25; ++k){
      const int t2 = 2*k + p;                          // wave-uniform
      const uint32_t K0 = keys[t2*4+0], K1 = keys[t2*4+1];  // s_load
      const uint32_t K2 = keys[t2*4+2], K3 = keys[t2*4+3];
      if (!done){
        const float u1 = bits_to_unit(tf_bits32(K0, K1, (uint32_t)row));
        const float u2 = bits_to_unit(tf_bits32(K2, K3, (uint32_t)row));
        const float wc   = 2.0f * u1 - 1.0f;
        const float omw2 = fmaxf(1.0f - wc*wc, 1e-38f);
        const float lp   = kappa * wc + 14.5f * alogf(omw2);
        const float lr   = alogf(u2 + 1e-38f);
        if (lr + kappa <= lp){ done = true; idx = t2; myw = wc; }
      }
      if (__ballot(!done) == 0ull) break;              // whole wave's rows accepted
    }
  }
  idxsh[p*128 + r] = idx;
  wsh [p*128 + r] = myw;

  // normals: j = 2i+p (p=0: 16 evens, p=1: 15 odds)
  {
    const uint32_t kv0 = keys[200], kv1 = keys[201];
    const uint32_t e0 = (uint32_t)row * 31u;
    #pragma unroll
    for (int i = 0; i < 16; ++i){
      const int j = 2*i + p;                           // wave-uniform predicate
      if (j < 31){
        const float uf01 = bits_to_unit(tf_bits32(kv0, kv1, e0 + (uint32_t)j));
        const float uu = fmaxf(uf01 * 2.0f + (-0.99999994f), -0.99999994f);
        vsh[r*33 + j] = 1.4142135623730951f * erfinv_f(uu);
      }
    }
  }
  __syncthreads();

  // combine first-accept (min try index; even/odd disjoint -> bit-exact)
  float w;
  {
    int   i0 = idxsh[r], i1 = idxsh[128 + r];
    float w0 = wsh[r],   w1 = wsh[128 + r];
    w = (i0 < i1) ? ((i0 < NTRY) ? w0 : 0.f) : ((i1 < NTRY) ? w1 : 0.f);
  }
  w = fminf(fmaxf(w, -1.0f), 1.0f);

  float vns = 0.f;
  #pragma unroll
  for (int j = 0; j < 31; ++j){ float g = vsh[r*33 + j]; vns += g*g; }
  const float invvn = 1.0f / fmaxf(sqrtf(vns), 1e-12f);
  const float st    = sqrtf(fmaxf(1.0f - w*w, 1e-38f));

  // Householder: same op order as R2 -> z bit-identical
  float uns = 0.f;
  #pragma unroll
  for (int o = 0; o < 32; ++o){
    float mu_n = mush[r*33 + o] * invn;
    float e = ((o == 31) ? 1.0f : 0.0f) - mu_n;
    uns += e*e;
  }
  const float invun = 1.0f / fmaxf(sqrtf(uns), 1e-12f);
  float dot = 0.f;
  #pragma unroll
  for (int o = 0; o < 32; ++o){
    float mu_n = mush[r*33 + o] * invn;
    float ue = (((o == 31) ? 1.0f : 0.0f) - mu_n) * invun;
    float zt = (o < 31) ? st * (vsh[r*33 + o] * invvn) : w;
    dot += zt * ue;
  }
  float z[32];
  #pragma unroll
  for (int o = 0; o < 32; ++o){
    float mu_n = mush[r*33 + o] * invn;
    float ue = (((o == 31) ? 1.0f : 0.0f) - mu_n) * invun;
    float zt = (o < 31) ? st * (vsh[r*33 + o] * invvn) : w;
    z[o] = zt - 2.0f * dot * ue;
  }

  // ---------- phase C: MLP; o1 split 256/256; deterministic 2-partial reduce -------
  __syncthreads();   // everyone done reading mush/vsh before reuse as partial bufs

  float x2p[32];
  #pragma unroll
  for (int o2 = 0; o2 < 32; ++o2) x2p[o2] = (p == 0) ? b2[o2] : 0.f;
  const int o1base = p * 256;
  #pragma unroll 2
  for (int q = 0; q < 256; ++q){
    const int o1 = o1base + q;
    const float* w1r = W1 + o1*32;       // wave-uniform -> s_load
    float t = b1[o1];
    #pragma unroll
    for (int j = 0; j < 32; ++j) t += z[j] * w1r[j];
    t = fmaxf(t, 0.f);
    const float* w2r = W2T + o1*32;      // wave-uniform -> s_load
    #pragma unroll
    for (int o2 = 0; o2 < 32; ++o2) x2p[o2] += t * w2r[o2];
  }
  {
    float* dst = (p == 0) ? (mush + r*33) : (vsh + r*33);
    #pragma unroll
    for (int o2 = 0; o2 < 32; ++o2) dst[o2] = x2p[o2];
  }
  __syncthreads();

  // epilogue: p=0 -> out k=0..3; p=1 -> k=4..6
  const int kbeg = (p == 0) ? 0 : 4;
  const int kend = (p == 0) ? 4 : 7;
  for (int kk = kbeg; kk < kend; ++kk){
    const float* w3r = W3 + kk*32;       // wave-uniform -> s_load
    float s = b3[kk];
    #pragma unroll
    for (int o2 = 0; o2 < 32; ++o2){
      float x2 = fmaxf(mush[r*33 + o2] + vsh[r*33 + o2], 0.f);
      s += x2 * w3r[o2];
    }
    out[(size_t)row*7 + kk] = s;
  }
}

extern "C" void kernel_launch(void* const* d_in, const int* in_sizes, int n_in,
                              void* d_out, int out_size, void* d_ws, size_t ws_size,
                              hipStream_t stream)
{
  const float* h   = (const float*)d_in[0];
  const float* Wmu = (const float*)d_in[1];
  const float* bmu = (const float*)d_in[2];
  const float* Wk  = (const float*)d_in[3];
  const float* bk  = (const float*)d_in[4];
  const float* W1  = (const float*)d_in[5];
  const float* b1  = (const float*)d_in[6];
  const float* W2  = (const float*)d_in[7];
  const float* b2  = (const float*)d_in[8];
  const float* W3  = (const float*)d_in[9];
  const float* b3  = (const float*)d_in[10];
  const int* seed  = (const int*)d_in[11];

  uint32_t* keys = (uint32_t*)d_ws;
  float* W2T = (float*)((char*)d_ws + 1024);
  float* out = (float*)d_out;

  hipLaunchKernelGGL(prep_kernel, dim3(32), dim3(256), 0, stream, W2, seed, keys, W2T);
  hipLaunchKernelGGL(fused_kernel, dim3(BROWS/128), dim3(256), 0, stream,
                     h, Wmu, bmu, Wk, bk, W1, b1, b2, W3, b3, W2T, keys, out);
}

// Round 5
// 1233.628 us; speedup vs baseline: 3.3556x; 3.3400x over previous
//
#include <hip/hip_runtime.h>
#include <math.h>
#include <stdint.h>

#define NTRY  50
#define BROWS 131072
// output section offsets (floats): out[B*7] | mu[B*32] | kappa[B]
#define OFF_OUT_MU    917504
#define OFF_OUT_KAPPA 5111808

// ws layout (bytes): keys @0 (808, padded to 1024) | W2T @1024 (64KB)
//                    w_ws @66560 (512KB) | v_ws @590848 (B*31*4)
#define WS_W2T   1024
#define WS_W     66560
#define WS_V     590848

__device__ __forceinline__ uint32_t rotl32(uint32_t x, int r){ return (x << r) | (x >> (32 - r)); }

// Exact JAX threefry2x32 (20 rounds, 5 key injections)
__device__ __forceinline__ void threefry2x32(uint32_t k0, uint32_t k1,
                                             uint32_t c0, uint32_t c1,
                                             uint32_t& o0, uint32_t& o1){
  const uint32_t k2 = k0 ^ k1 ^ 0x1BD11BDAu;
  uint32_t x0 = c0 + k0;
  uint32_t x1 = c1 + k1;
#define TF_R(r) { x0 += x1; x1 = rotl32(x1, (r)); x1 ^= x0; }
  TF_R(13) TF_R(15) TF_R(26) TF_R(6)
  x0 += k1; x1 += k2 + 1u;
  TF_R(17) TF_R(29) TF_R(16) TF_R(24)
  x0 += k2; x1 += k0 + 2u;
  TF_R(13) TF_R(15) TF_R(26) TF_R(6)
  x0 += k0; x1 += k1 + 3u;
  TF_R(17) TF_R(29) TF_R(16) TF_R(24)
  x0 += k1; x1 += k2 + 4u;
  TF_R(13) TF_R(15) TF_R(26) TF_R(6)
  x0 += k2; x1 += k0 + 5u;
#undef TF_R
  o0 = x0; o1 = x1;
}

// Partitionable random_bits (bit_width=32): bits = out0 ^ out1, counter=(0, idx)
__device__ __forceinline__ uint32_t tf_bits32(uint32_t k0, uint32_t k1, uint32_t idx){
  uint32_t a, b;
  threefry2x32(k0, k1, 0u, idx, a, b);
  return a ^ b;
}

// JAX uniform bit->float: (bits>>9)|0x3f800000 as float, minus 1 -> [0,1)
__device__ __forceinline__ float bits_to_unit(uint32_t bits){
  return __uint_as_float((bits >> 9) | 0x3f800000u) - 1.0f;
}

// f32 log via f64 (≈ correctly rounded) — feeds acceptance ties, keep exact
__device__ __forceinline__ float alogf(float x){
  return (float)log((double)x);
}

// XLA f32 ErfInv polynomial (Giles)
__device__ __forceinline__ float erfinv_f(float x){
  float w = -log1pf(-x * x);
  float p;
  if (w < 5.0f){
    w -= 2.5f;
    p = 2.81022636e-08f;
    p = fmaf(p, w, 3.43273939e-07f);
    p = fmaf(p, w, -3.5233877e-06f);
    p = fmaf(p, w, -4.39150654e-06f);
    p = fmaf(p, w, 0.00021858087f);
    p = fmaf(p, w, -0.00125372503f);
    p = fmaf(p, w, -0.00417768164f);
    p = fmaf(p, w, 0.246640727f);
    p = fmaf(p, w, 1.50140941f);
  } else {
    w = sqrtf(w) - 3.0f;
    p = -0.000200214257f;
    p = fmaf(p, w, 0.000100950558f);
    p = fmaf(p, w, 0.00134934322f);
    p = fmaf(p, w, -0.00367342844f);
    p = fmaf(p, w, 0.00573950773f);
    p = fmaf(p, w, -0.0076224613f);
    p = fmaf(p, w, 0.00943887047f);
    p = fmaf(p, w, 1.00167406f);
    p = fmaf(p, w, 2.83297682f);
  }
  return p * x;
}

// prep: keys u32[0..200) = 50 * {k1.x,k1.y,k2.x,k2.y}; u32[200..202) = kv; W2T transpose
__global__ void prep_kernel(const float* __restrict__ W2, const int* __restrict__ seedp,
                            uint32_t* __restrict__ keys, float* __restrict__ W2T)
{
  const int t = threadIdx.x;
  if (blockIdx.x == 0){
    const uint32_t seed = (uint32_t)seedp[0];
    if (t < NTRY){
      uint32_t f0, f1, a0, a1, b0, b1;
      threefry2x32(0u, seed, 0u, (uint32_t)t, f0, f1);
      threefry2x32(f0, f1, 0u, 0u, a0, a1);   // k1 = split[0]
      threefry2x32(f0, f1, 0u, 1u, b0, b1);   // k2 = split[1]
      keys[t*4+0] = a0; keys[t*4+1] = a1;
      keys[t*4+2] = b0; keys[t*4+3] = b1;
    } else if (t == NTRY){
      uint32_t f0, f1;
      threefry2x32(0u, seed, 0u, 10000u, f0, f1);
      keys[200] = f0; keys[201] = f1;
    }
  }
  const int base = blockIdx.x * 512;
  for (int i = base + t; i < base + 512; i += 256){
    int o2 = i >> 9, o1 = i & 511;
    W2T[o1*32 + o2] = W2[i];
  }
}

// ---------------- K1: encode. 64 rows x 4 colgroup-waves per block. -----------------
// Each thread: 8 FULL-K sequential mu dots (bit-identical chains to R2).
// Wave g==3 additionally computes the kappa dot fully sequentially (R2 bits).
// Wave g==0 does mu normalization + writes normalized mu to out.
// NO min-waves clause: live set ~60 VGPR, occupancy from 8192-wave grid.
__global__ __launch_bounds__(256) void k1_encode(
    const float* __restrict__ h,
    const float* __restrict__ Wmu, const float* __restrict__ bmu,
    const float* __restrict__ Wk,  const float* __restrict__ bk,
    float* __restrict__ out)
{
  __shared__ float mush[64*33];   // raw mu+bias, stride 33 (conflict-free)

  const int r   = threadIdx.x & 63;
  const int g   = threadIdx.x >> 6;     // colgroup, wave-uniform
  const int row = blockIdx.x * 64 + r;

  float acc[8]; float kacc = 0.f;
  #pragma unroll
  for (int i = 0; i < 8; ++i) acc[i] = 0.f;
  const float4* h4 = reinterpret_cast<const float4*>(h + (size_t)row * 512);
  const int obase = g * 8;

  #pragma unroll 1
  for (int ch = 0; ch < 16; ++ch){
    float hv[32];
    #pragma unroll
    for (int q = 0; q < 8; ++q){
      float4 f = h4[ch*8 + q];
      hv[q*4+0] = f.x; hv[q*4+1] = f.y; hv[q*4+2] = f.z; hv[q*4+3] = f.w;
    }
    #pragma unroll
    for (int i = 0; i < 8; ++i){
      const float* wr = Wmu + (obase + i)*512 + ch*32;   // wave-uniform -> s_load
      float a = acc[i];
      #pragma unroll
      for (int c = 0; c < 32; ++c) a += hv[c] * wr[c];
      acc[i] = a;
    }
    if (g == 3){                                          // wave-uniform branch
      const float* wr = Wk + ch*32;
      float a = kacc;
      #pragma unroll
      for (int c = 0; c < 32; ++c) a += hv[c] * wr[c];
      kacc = a;
    }
  }
  #pragma unroll
  for (int i = 0; i < 8; ++i) mush[r*33 + obase + i] = acc[i] + bmu[obase + i];
  if (g == 3){
    const float xk = kacc + bk[0];
    out[OFF_OUT_KAPPA + row] = (float)log1p(exp((double)xk)) + 1.0f;  // softplus+1
  }
  __syncthreads();

  if (g == 0){
    // nsq sequential over 32 -> bit-identical to R2
    float nsq = 0.f;
    #pragma unroll
    for (int o = 0; o < 32; ++o){ float m = mush[r*33 + o]; nsq += m*m; }
    const float invn = 1.0f / fmaxf(sqrtf(nsq), 1e-12f);
    float4* mo = reinterpret_cast<float4*>(out + OFF_OUT_MU + (size_t)row * 32);
    #pragma unroll
    for (int q = 0; q < 8; ++q){
      float4 f;
      f.x = mush[r*33 + q*4+0] * invn;
      f.y = mush[r*33 + q*4+1] * invn;
      f.z = mush[r*33 + q*4+2] * invn;
      f.w = mush[r*33 + q*4+3] * invn;
      mo[q] = f;
    }
  }
}

// ---------------- K2: sampling. 64 rows x 4 try/normal-slice waves. -----------------
// R3's phase-B logic verbatim (it PASSED). Tiny live set (~25 VGPR) -> full occupancy.
__global__ __launch_bounds__(256) void k2_sample(
    const uint32_t* __restrict__ keys,
    const float* __restrict__ out,        // kappa read from out (written by K1)
    float* __restrict__ w_ws,
    float* __restrict__ v_ws)
{
  __shared__ int   idxsh[256];
  __shared__ float wsh[256];

  const int r   = threadIdx.x & 63;
  const int sub = threadIdx.x >> 6;      // wave-uniform
  const int row = blockIdx.x * 64 + r;

  const float kappa = out[OFF_OUT_KAPPA + row];

  int idx = NTRY; float myw = 0.f;
  {
    #pragma clang fp contract(off)
    bool done = false;
    #pragma unroll 1
    for (int k = 0; k < 13; ++k){
      const int t4 = 4*k + sub;                          // wave-uniform
      const int tc = (t4 < NTRY) ? t4 : (NTRY - 1);
      const uint32_t K0 = keys[tc*4+0], K1 = keys[tc*4+1];  // s_load
      const uint32_t K2 = keys[tc*4+2], K3 = keys[tc*4+3];
      if (t4 < NTRY && !done){
        const float u1 = bits_to_unit(tf_bits32(K0, K1, (uint32_t)row));
        const float u2 = bits_to_unit(tf_bits32(K2, K3, (uint32_t)row));
        const float wc   = 2.0f * u1 - 1.0f;
        const float omw2 = fmaxf(1.0f - wc*wc, 1e-38f);
        const float lp   = kappa * wc + 14.5f * alogf(omw2);
        const float lr   = alogf(u2 + 1e-38f);
        if (lr + kappa <= lp){ done = true; idx = t4; myw = wc; }
      }
      const bool fin = done || (4*(k+1) + sub >= NTRY);
      if (__ballot(!fin) == 0ull) break;
    }
  }
  idxsh[sub*64 + r] = idx;
  wsh [sub*64 + r] = myw;

  // normals: wave sub computes j in {sub, sub+4, ...} -> v_ws[row*31+j]
  {
    const uint32_t kv0 = keys[200], kv1 = keys[201];
    const uint32_t e0 = (uint32_t)row * 31u;
    #pragma unroll
    for (int i = 0; i < 8; ++i){
      const int j = 4*i + sub;                           // wave-uniform predicate
      if (j < 31){
        const float uf01 = bits_to_unit(tf_bits32(kv0, kv1, e0 + (uint32_t)j));
        const float uu = fmaxf(uf01 * 2.0f + (-0.99999994f), -0.99999994f);
        v_ws[(size_t)row*31 + j] = 1.4142135623730951f * erfinv_f(uu);
      }
    }
  }
  __syncthreads();

  if (sub == 0){
    int bidx = NTRY; float w = 0.f;
    #pragma unroll
    for (int s = 0; s < 4; ++s){
      int   ii = idxsh[s*64 + r];
      float ww = wsh [s*64 + r];
      if (ii < bidx){ bidx = ii; w = ww; }
    }
    w_ws[row] = fminf(fmaxf(w, -1.0f), 1.0f);   // store post-clamp w
  }
}

// ---------------- K3: z-assemble + MLP. 128 rows x 2 o1-halves. ---------------------
// Live set peak ~110 VGPR with NO occupancy clause -> compiler allocates freely,
// 4 waves/SIMD natural, NO spills (the R3/R4 failure mode).
__global__ __launch_bounds__(256) void k3_mlp(
    const float* __restrict__ out_ro,     // normalized mu (written by K1)
    const float* __restrict__ w_ws,
    const float* __restrict__ v_ws,
    const float* __restrict__ W1,  const float* __restrict__ b1,
    const float* __restrict__ b2,
    const float* __restrict__ W3,  const float* __restrict__ b3,
    const float* __restrict__ W2T,
    float* __restrict__ out)
{
  __shared__ float xash[128*33];   // p=0 partial (incl b2)
  __shared__ float xbsh[128*33];   // p=1 partial

  const int r   = threadIdx.x & 127;
  const int p   = threadIdx.x >> 7;      // wave-uniform
  const int row = blockIdx.x * 128 + r;

  // load normalized mu (bits identical to R2's mush*invn products)
  float mu_n[32];
  {
    const float4* mi = reinterpret_cast<const float4*>(out_ro + OFF_OUT_MU + (size_t)row * 32);
    #pragma unroll
    for (int q = 0; q < 8; ++q){
      float4 f = mi[q];
      mu_n[q*4+0] = f.x; mu_n[q*4+1] = f.y; mu_n[q*4+2] = f.z; mu_n[q*4+3] = f.w;
    }
  }
  const float w = w_ws[row];
  float v[31];
  #pragma unroll
  for (int j = 0; j < 31; ++j) v[j] = v_ws[(size_t)row*31 + j];

  // vns sequential (R2 order)
  float vns = 0.f;
  #pragma unroll
  for (int j = 0; j < 31; ++j) vns += v[j] * v[j];
  const float invvn = 1.0f / fmaxf(sqrtf(vns), 1e-12f);
  const float st    = sqrtf(fmaxf(1.0f - w*w, 1e-38f));

  // Householder — exact R2 expression sequence
  float uns = 0.f;
  #pragma unroll
  for (int o = 0; o < 32; ++o){
    float e = ((o == 31) ? 1.0f : 0.0f) - mu_n[o];
    uns += e*e;
  }
  const float invun = 1.0f / fmaxf(sqrtf(uns), 1e-12f);
  float dot = 0.f;
  #pragma unroll
  for (int o = 0; o < 32; ++o){
    float ue = (((o == 31) ? 1.0f : 0.0f) - mu_n[o]) * invun;
    float zt = (o < 31) ? st * (v[o] * invvn) : w;
    dot += zt * ue;
  }
  float z[32];
  #pragma unroll
  for (int o = 0; o < 32; ++o){
    float ue = (((o == 31) ? 1.0f : 0.0f) - mu_n[o]) * invun;
    float zt = (o < 31) ? st * (v[o] * invvn) : w;
    z[o] = zt - 2.0f * dot * ue;
  }

  // MLP half (R4-proven combine): o1 in [p*256, p*256+256)
  float x2p[32];
  #pragma unroll
  for (int o2 = 0; o2 < 32; ++o2) x2p[o2] = (p == 0) ? b2[o2] : 0.f;
  const int o1base = p * 256;
  #pragma unroll 2
  for (int q = 0; q < 256; ++q){
    const int o1 = o1base + q;
    const float* w1r = W1 + o1*32;       // wave-uniform -> s_load
    float t = b1[o1];
    #pragma unroll
    for (int j = 0; j < 32; ++j) t += z[j] * w1r[j];
    t = fmaxf(t, 0.f);
    const float* w2r = W2T + o1*32;      // wave-uniform -> s_load
    #pragma unroll
    for (int o2 = 0; o2 < 32; ++o2) x2p[o2] += t * w2r[o2];
  }
  {
    float* dst = (p == 0) ? (xash + r*33) : (xbsh + r*33);
    #pragma unroll
    for (int o2 = 0; o2 < 32; ++o2) dst[o2] = x2p[o2];
  }
  __syncthreads();

  const int kbeg = (p == 0) ? 0 : 4;
  const int kend = (p == 0) ? 4 : 7;
  for (int kk = kbeg; kk < kend; ++kk){
    const float* w3r = W3 + kk*32;       // wave-uniform -> s_load
    float s = b3[kk];
    #pragma unroll
    for (int o2 = 0; o2 < 32; ++o2){
      float x2 = fmaxf(xash[r*33 + o2] + xbsh[r*33 + o2], 0.f);
      s += x2 * w3r[o2];
    }
    out[(size_t)row*7 + kk] = s;
  }
}

extern "C" void kernel_launch(void* const* d_in, const int* in_sizes, int n_in,
                              void* d_out, int out_size, void* d_ws, size_t ws_size,
                              hipStream_t stream)
{
  const float* h   = (const float*)d_in[0];
  const float* Wmu = (const float*)d_in[1];
  const float* bmu = (const float*)d_in[2];
  const float* Wk  = (const float*)d_in[3];
  const float* bk  = (const float*)d_in[4];
  const float* W1  = (const float*)d_in[5];
  const float* b1  = (const float*)d_in[6];
  const float* W2  = (const float*)d_in[7];
  const float* b2  = (const float*)d_in[8];
  const float* W3  = (const float*)d_in[9];
  const float* b3  = (const float*)d_in[10];
  const int* seed  = (const int*)d_in[11];

  uint32_t* keys = (uint32_t*)d_ws;
  float* W2T  = (float*)((char*)d_ws + WS_W2T);
  float* w_ws = (float*)((char*)d_ws + WS_W);
  float* v_ws = (float*)((char*)d_ws + WS_V);
  float* out  = (float*)d_out;

  hipLaunchKernelGGL(prep_kernel, dim3(32), dim3(256), 0, stream, W2, seed, keys, W2T);
  hipLaunchKernelGGL(k1_encode,  dim3(BROWS/64),  dim3(256), 0, stream,
                     h, Wmu, bmu, Wk, bk, out);
  hipLaunchKernelGGL(k2_sample,  dim3(BROWS/64),  dim3(256), 0, stream,
                     keys, out, w_ws, v_ws);
  hipLaunchKernelGGL(k3_mlp,     dim3(BROWS/128), dim3(256), 0, stream,
                     out, w_ws, v_ws, W1, b1, b2, W3, b3, W2T, out);
}